// Round 12
// baseline (682.364 us; speedup 1.0000x reference)
//
#include <hip/hip_runtime.h>
#include <stdint.h>

// Problem: B=2, S=2048, D=2048, H=16, HD=128, M = B*S = 4096
#define BB  2
#define SS  2048
#define DD  2048
#define HH  16
#define HDD 128
#define MM  (BB * SS)

typedef __attribute__((ext_vector_type(8)))  short short8;
typedef __attribute__((ext_vector_type(4)))  float f32x4;
typedef __attribute__((ext_vector_type(16))) float f32x16;
typedef unsigned int   u32;
typedef unsigned short u16;
typedef __attribute__((ext_vector_type(4))) u16 u16x4;
typedef __attribute__((ext_vector_type(2))) u32 u32x2;
typedef __attribute__((ext_vector_type(4))) u32 u32x4;

static __device__ __forceinline__ u16 f2bf(float f) {
  u32 u = __builtin_bit_cast(u32, f);
  u32 r = u + 0x7fffu + ((u >> 16) & 1u);
  return (u16)(r >> 16);
}

static __device__ __forceinline__ u32 cvtpk(float a, float b) {
  u32 r;
  asm("v_cvt_pk_bf16_f32 %0, %1, %2" : "=v"(r) : "v"(a), "v"(b));
  return r;
}
static __device__ __forceinline__ void permswap(u32& a, u32& b) {
  asm volatile("v_permlane32_swap_b32 %0, %1" : "+v"(a), "+v"(b));
}

// ---------------- fused fp32 -> bf16 conversion, grid-strided ----------------
__global__ void cvt_all(const float* __restrict__ x,  const float* __restrict__ wq,
                        const float* __restrict__ wk, const float* __restrict__ wv,
                        const float* __restrict__ wo,
                        u16* __restrict__ xb, u16* __restrict__ wqkv,
                        u16* __restrict__ wob) {
  const int NX = (MM * DD) / 4;        // 2097152 chunks for x
  const int NW = (DD * DD) / 4;        // 1048576 chunks per weight
  const int total = NX + 4 * NW;       // 6291456
  for (int i = blockIdx.x * blockDim.x + threadIdx.x; i < total;
       i += gridDim.x * blockDim.x) {
    const float* s; u16* d; int off;
    if (i < NX) { s = x; d = xb; off = i; }
    else {
      int j = i - NX; int w = j >> 20; off = j & (NW - 1);
      s = (w == 0) ? wq : (w == 1) ? wk : (w == 2) ? wv : wo;
      d = (w < 3) ? (wqkv + (size_t)w * DD * DD) : wob;
    }
    f32x4 v = *(const f32x4*)(s + (size_t)off * 4);
    u16x4 o;
#pragma unroll
    for (int j = 0; j < 4; ++j) o[j] = f2bf(v[j]);
    *(u16x4*)(d + (size_t)off * 4) = o;
  }
}

// ---------------- GEMM: C[M,N] = A[M,K] * B[N,K]^T ----------------
// 128x128 tile, 4 waves, BK=64, SINGLE-buffered LDS (32 KB -> 5 blocks/CU,
// 20 waves/CU: m97's occupancy recipe — implicit cross-block wave overlap
// hides the staging drain; m99/m132 showed explicit dbuf trades occupancy at
// a net loss). Chunk-XOR swizzle (source c^=(row&7), read (ks*4+kh)^(lrow&7))
// -> 0 bank conflicts (R10-proven). XCD-aware bijective block swizzle (1D grid).
// MODE 1: f32 out row-major (O-projection)
// MODE 4: QKV fused epilogue — region 0: rope*scale->Cq; 1: rope->Ck; 2: V^T->Cvt
template <int MODE>
__global__ __launch_bounds__(256, 5) void gemm2(const u16* __restrict__ A,
                                                const u16* __restrict__ Bw,
                                                u16* __restrict__ Cq,
                                                u16* __restrict__ Ck,
                                                u16* __restrict__ Cvt,
                                                float* __restrict__ Cf,
                                                int M, int N, int K, int nbx,
                                                const float* __restrict__ fc,
                                                const float* __restrict__ fs) {
  __shared__ __align__(16) u16 Al[128 * 64];
  __shared__ __align__(16) u16 Bl[128 * 64];
  const int tid  = threadIdx.x;
  const int wave = tid >> 6, lane = tid & 63;
  // XCD-aware bijective remap: gridDim.x % 8 == 0 (1536 / 512)
  const int cpx = gridDim.x >> 3;
  const int bid = blockIdx.x;
  const int swzb = (bid & 7) * cpx + (bid >> 3);
  const int bx = swzb % nbx, by = swzb / nbx;
  const int m0 = by * 128, n0 = bx * 128;
  const int wr = (wave >> 1) * 64, wc = (wave & 1) * 64;
  const int lrow = lane & 15, kh = lane >> 4;
  const int sk = lrow & 7;             // read-side swizzle key

  f32x4 acc[4][4] = {};

  // stage K-tile T (A 128x64 + B 128x64): 8 loads/thread, linear LDS dest,
  // global source chunk pre-swizzled c ^= (row&7).
#define GSTAGE(T)                                                                       \
  {                                                                                     \
    int koff = (T) * 64;                                                                \
    _Pragma("unroll")                                                                   \
    for (int j_ = 0; j_ < 4; ++j_) {                                                    \
      int i_ = tid + j_ * 256;            /* 0..1023 */                                 \
      int r_ = i_ >> 3, c_ = i_ & 7;                                                    \
      int sc_ = (c_ ^ (r_ & 7)) * 8;                                                    \
      const u16* ga = A  + (size_t)(m0 + r_) * K + koff + sc_;                          \
      __builtin_amdgcn_global_load_lds((const __attribute__((address_space(1))) u32*)ga,\
                                       (__attribute__((address_space(3))) u32*)(Al + i_ * 8), \
                                       16, 0, 0);                                       \
      const u16* gb = Bw + (size_t)(n0 + r_) * K + koff + sc_;                          \
      __builtin_amdgcn_global_load_lds((const __attribute__((address_space(1))) u32*)gb,\
                                       (__attribute__((address_space(3))) u32*)(Bl + i_ * 8), \
                                       16, 0, 0);                                       \
    }                                                                                   \
  }

  const int NT = K / 64;               // 32
  for (int t = 0; t < NT; ++t) {
    if (t) __syncthreads();            // all reads of tile t-1 done before overwrite
    GSTAGE(t);
    __syncthreads();                   // drains vmcnt -> tile t visible block-wide

    short8 af[4][2], bf[4][2];
#pragma unroll
    for (int tt = 0; tt < 4; ++tt)
#pragma unroll
      for (int ks = 0; ks < 2; ++ks) {
        af[tt][ks] = *(const short8*)(Al + (wr + tt * 16 + lrow) * 64 + ((ks * 4 + kh) ^ sk) * 8);
        bf[tt][ks] = *(const short8*)(Bl + (wc + tt * 16 + lrow) * 64 + ((ks * 4 + kh) ^ sk) * 8);
      }
#pragma unroll
    for (int mt = 0; mt < 4; ++mt)
#pragma unroll
      for (int nt = 0; nt < 4; ++nt)
#pragma unroll
        for (int ks = 0; ks < 2; ++ks)
          acc[mt][nt] = __builtin_amdgcn_mfma_f32_16x16x32_bf16(af[mt][ks], bf[nt][ks], acc[mt][nt], 0, 0, 0);
  }
#undef GSTAGE

  const int dr = kh * 4;
  if constexpr (MODE == 1) {
#pragma unroll
    for (int mt = 0; mt < 4; ++mt)
#pragma unroll
      for (int nt = 0; nt < 4; ++nt)
#pragma unroll
        for (int i = 0; i < 4; ++i) {
          size_t r = (size_t)(m0 + wr + mt * 16 + dr + i);
          size_t c = (size_t)(n0 + wc + nt * 16 + lrow);
          Cf[r * N + c] = acc[mt][nt][i];
        }
  } else {
    const int region = n0 >> 11;        // 0:Q 1:K 2:V  (block-uniform)
    if (region < 2) {
      u16* Cd = region ? Ck : Cq;
      // Q pre-scaled by 1/sqrt(128)*log2e (attn works in exp2 domain)
      const float sfac = region ? 1.f : 0.08838834764831845f * 1.44269504088896340736f;
#pragma unroll
      for (int mt = 0; mt < 4; ++mt)
#pragma unroll
        for (int nt = 0; nt < 4; ++nt) {
          int c  = n0 + wc + nt * 16 + lrow;
          int cl = c & 2047;
          int dh = cl & 127, pi = dh >> 1;
          float sgn = (dh & 1) ? 1.f : -1.f;
#pragma unroll
          for (int i = 0; i < 4; ++i) {
            int r  = m0 + wr + mt * 16 + dr + i;
            int s_ = r & (SS - 1);
            float cc_ = fc[s_ * 64 + pi] * sfac;
            float ss_ = fs[s_ * 64 + pi] * (sgn * sfac);
            float v  = acc[mt][nt][i];
            float pv = __shfl_xor(v, 1, 64);
            Cd[(size_t)r * 2048 + cl] = f2bf(v * cc_ + pv * ss_);
          }
        }
    } else {
#pragma unroll
      for (int mt = 0; mt < 4; ++mt)
#pragma unroll
        for (int nt = 0; nt < 4; ++nt) {
          int cl = (n0 - 4096) + wc + nt * 16 + lrow;   // h*128+d
          int rr = m0 + wr + mt * 16 + dr;              // token, multiple of 4
          int b  = rr >> 11, s0 = rr & 2047;
          u16x4 pk;
#pragma unroll
          for (int i = 0; i < 4; ++i) pk[i] = f2bf(acc[mt][nt][i]);
          *(u16x4*)(Cvt + ((size_t)b * 2048 + cl) * 2048 + s0) = pk;
        }
    }
  }
}

// ---------------- Flash attention (causal), swapped 32x32, 2 blocks/CU ----------------
// (unchanged from R10)
__global__ __launch_bounds__(256, 2) void attn_kernel(const u16* __restrict__ Q,
                                                      const u16* __restrict__ K,
                                                      const u16* __restrict__ Vt,
                                                      u16* __restrict__ O) {
  __shared__ __align__(16) u16 Kl[2][64 * 128];   // [buf][key][d], swizzled
  __shared__ __align__(16) u16 Vl[2][128 * 64];   // [buf][d][key], swizzled

  const int tid = threadIdx.x, wave = tid >> 6, lane = tid & 63;
  const int l31 = lane & 31, hi = lane >> 5;
  const int bh = blockIdx.x, b = bh >> 4, h = bh & 15;
  const int y = blockIdx.y;
  const int qt = (y < 8) ? y : (23 - y);
  const size_t base    = ((size_t)b * SS) * DD + (size_t)h * HDD;
  const size_t vt_base = (size_t)bh * HDD * SS;
  const int swz = (l31 & 7) << 4;                 // byte-domain LDS read swizzle

#define STAGE(KT, BUF)                                                              \
  {                                                                                 \
    int k0s = (KT) * 64;                                                            \
    _Pragma("unroll")                                                               \
    for (int i_ = 0; i_ < 4; ++i_) {                                                \
      int idx = tid + i_ * 256;                                                     \
      int kr = idx >> 4, c_ = idx & 15;                                             \
      const u16* gk = K + base + (size_t)(k0s + kr) * DD + ((c_ ^ (kr & 7)) * 8);   \
      __builtin_amdgcn_global_load_lds((const __attribute__((address_space(1))) u32*)gk, \
                                       (__attribute__((address_space(3))) u32*)(&Kl[BUF][0] + idx * 8), \
                                       16, 0, 0);                                   \
      int dv = idx >> 3, c2 = idx & 7;                                              \
      const u16* gv = Vt + vt_base + (size_t)dv * SS + k0s + ((c2 ^ (dv & 7)) * 8); \
      __builtin_amdgcn_global_load_lds((const __attribute__((address_space(1))) u32*)gv, \
                                       (__attribute__((address_space(3))) u32*)(&Vl[BUF][0] + idx * 8), \
                                       16, 0, 0);                                   \
    }                                                                               \
  }

  const int qw = qt * 128 + wave * 32;
  const int q_ = qw + l31;

  short8 qf[8];
#pragma unroll
  for (int kc = 0; kc < 8; ++kc)
    qf[kc] = *(const short8*)(Q + base + (size_t)(qw + l31) * DD + kc * 16 + hi * 8);

  f32x16 oacc[4] = {};
  float m_i = -1e30f, l_p = 0.f;

  int buf = 0;
  STAGE(0, 0);

  const int ntiles = 2 * qt + 2;
  for (int kt = 0; kt < ntiles; ++kt) {
    const int k0 = kt * 64;
    if (kt + 1 < ntiles) {
      STAGE(kt + 1, buf ^ 1);
      asm volatile("s_waitcnt vmcnt(8)" ::: "memory");
    } else {
      asm volatile("s_waitcnt vmcnt(0)" ::: "memory");
    }
    __builtin_amdgcn_s_barrier();

    if (k0 <= qw + 31) {
      const u16* Kb_ = &Kl[buf][0];
      const u16* Vb_ = &Vl[buf][0];

      f32x16 st[2] = {};
      __builtin_amdgcn_s_setprio(1);
#pragma unroll
      for (int kc = 0; kc < 8; ++kc) {
        int by0 = (l31 * 256)        + ((kc * 32 + hi * 16) ^ swz);
        int by1 = ((32 + l31) * 256) + ((kc * 32 + hi * 16) ^ swz);
        short8 a0 = *(const short8*)(Kb_ + (by0 >> 1));
        short8 a1 = *(const short8*)(Kb_ + (by1 >> 1));
        st[0] = __builtin_amdgcn_mfma_f32_32x32x16_bf16(a0, qf[kc], st[0], 0, 0, 0);
        st[1] = __builtin_amdgcn_mfma_f32_32x32x16_bf16(a1, qf[kc], st[1], 0, 0, 0);
      }
      __builtin_amdgcn_s_setprio(0);

      float mx = -1e30f;
      if (k0 + 63 > qw) {                           // diagonal tile only
#pragma unroll
        for (int kb = 0; kb < 2; ++kb)
#pragma unroll
          for (int r = 0; r < 16; ++r) {
            float s = st[kb][r];
            int key = k0 + kb * 32 + (r & 3) + ((r >> 2) << 3) + (hi << 2);
            if (key > q_) s = -1e30f;
            st[kb][r] = s;
            mx = fmaxf(mx, s);
          }
      } else {
#pragma unroll
        for (int kb = 0; kb < 2; ++kb)
#pragma unroll
          for (int r = 0; r < 16; ++r) mx = fmaxf(mx, st[kb][r]);
      }
      mx = fmaxf(mx, __shfl_xor(mx, 32, 64));

      if (__any(mx > m_i + 8.f)) {
        float mn  = fmaxf(m_i, mx);
        float esc = exp2f(m_i - mn);
        m_i = mn; l_p *= esc;
#pragma unroll
        for (int db = 0; db < 4; ++db)
#pragma unroll
          for (int r = 0; r < 16; ++r) oacc[db][r] *= esc;
      }
      float sum = 0.f;
#pragma unroll
      for (int kb = 0; kb < 2; ++kb)
#pragma unroll
        for (int r = 0; r < 16; ++r) {
          float e = exp2f(st[kb][r] - m_i);
          st[kb][r] = e;
          sum += e;
        }
      l_p += sum;

      __builtin_amdgcn_s_setprio(1);
#pragma unroll
      for (int kb = 0; kb < 2; ++kb) {
#pragma unroll
        for (int half = 0; half < 2; ++half) {
          const int rb = half * 8;
          u32 w0 = cvtpk(st[kb][rb + 0], st[kb][rb + 1]);
          u32 w1 = cvtpk(st[kb][rb + 2], st[kb][rb + 3]);
          u32 w2 = cvtpk(st[kb][rb + 4], st[kb][rb + 5]);
          u32 w3 = cvtpk(st[kb][rb + 6], st[kb][rb + 7]);
          permswap(w0, w2);
          permswap(w1, w3);
          short8 pf = __builtin_bit_cast(short8, (u32x4){w0, w1, w2, w3});
          const int ktv = kb * 2 + half;
#pragma unroll
          for (int db = 0; db < 4; ++db) {
            int d = db * 32 + l31;
            int by = d * 128 + ((ktv * 32 + hi * 16) ^ swz);
            short8 vf = *(const short8*)(Vb_ + (by >> 1));
            oacc[db] = __builtin_amdgcn_mfma_f32_32x32x16_bf16(vf, pf, oacc[db], 0, 0, 0);
          }
        }
      }
      __builtin_amdgcn_s_setprio(0);
    }
    __builtin_amdgcn_s_barrier();       // all reads of buf done before restage
    buf ^= 1;
  }

  float lt  = l_p + __shfl_xor(l_p, 32, 64);
  float inv = 1.f / lt;
#pragma unroll
  for (int db = 0; db < 4; ++db)
#pragma unroll
    for (int g = 0; g < 4; ++g) {
      int d0 = db * 32 + 8 * g + 4 * hi;
      u32x2 pk;
      pk[0] = cvtpk(oacc[db][4 * g + 0] * inv, oacc[db][4 * g + 1] * inv);
      pk[1] = cvtpk(oacc[db][4 * g + 2] * inv, oacc[db][4 * g + 3] * inv);
      *(u32x2*)(O + base + (size_t)q_ * DD + d0) = pk;
    }
#undef STAGE
}

// ---------------- launcher ----------------
extern "C" void kernel_launch(void* const* d_in, const int* in_sizes, int n_in,
                              void* d_out, int out_size, void* d_ws, size_t ws_size,
                              hipStream_t stream) {
  (void)in_sizes; (void)n_in; (void)out_size; (void)ws_size;
  const float* x  = (const float*)d_in[0];
  const float* wq = (const float*)d_in[1];
  const float* wk = (const float*)d_in[2];
  const float* wv = (const float*)d_in[3];
  const float* wo = (const float*)d_in[4];
  const float* fc = (const float*)d_in[5];
  const float* fs = (const float*)d_in[6];
  float* out = (float*)d_out;

  const size_t XBUF = (size_t)MM * DD * 2;     // 16.78 MB
  const size_t WBUF = (size_t)DD * DD * 2;     // 8.39 MB
  char* ws = (char*)d_ws;
  u16* xb   = (u16*)(ws);                      // reused as attn output Ob
  u16* Qb   = (u16*)(ws + XBUF);
  u16* Kb   = (u16*)(ws + 2 * XBUF);
  u16* Vtb  = (u16*)(ws + 3 * XBUF);
  u16* wqkv = (u16*)(ws + 4 * XBUF);           // [6144][2048]
  u16* wob  = (u16*)(ws + 4 * XBUF + 3 * WBUF);
  u16* Ob   = xb;

  cvt_all<<<2048, 256, 0, stream>>>(x, wq, wk, wv, wo, xb, wqkv, wob);

  // fused QKV projection: C[4096, 6144] with rope/transpose epilogue
  gemm2<4><<<1536, 256, 0, stream>>>(xb, wqkv, Qb, Kb, Vtb, nullptr,
                                     MM, 3 * DD, DD, 48, fc, fs);

  attn_kernel<<<dim3(32, 16), 256, 0, stream>>>(Qb, Kb, Vtb, Ob);

  // O-projection: fp32 out
  gemm2<1><<<512, 256, 0, stream>>>(Ob, wob, nullptr, nullptr, nullptr, out,
                                    MM, DD, DD, 16, nullptr, nullptr);
}

// Round 13
// 248.090 us; speedup vs baseline: 2.7505x; 2.7505x over previous
//
#include <hip/hip_runtime.h>
#include <stdint.h>

// Problem: B=2, S=2048, D=2048, H=16, HD=128, M = B*S = 4096
#define BB  2
#define SS  2048
#define DD  2048
#define HH  16
#define HDD 128
#define MM  (BB * SS)

typedef __attribute__((ext_vector_type(8)))  short short8;
typedef __attribute__((ext_vector_type(4)))  float f32x4;
typedef __attribute__((ext_vector_type(16))) float f32x16;
typedef unsigned int   u32;
typedef unsigned short u16;
typedef __attribute__((ext_vector_type(4))) u16 u16x4;
typedef __attribute__((ext_vector_type(2))) u32 u32x2;
typedef __attribute__((ext_vector_type(4))) u32 u32x4;

static __device__ __forceinline__ u16 f2bf(float f) {
  u32 u = __builtin_bit_cast(u32, f);
  u32 r = u + 0x7fffu + ((u >> 16) & 1u);
  return (u16)(r >> 16);
}

static __device__ __forceinline__ u32 cvtpk(float a, float b) {
  u32 r;
  asm("v_cvt_pk_bf16_f32 %0, %1, %2" : "=v"(r) : "v"(a), "v"(b));
  return r;
}
static __device__ __forceinline__ void permswap(u32& a, u32& b) {
  asm volatile("v_permlane32_swap_b32 %0, %1" : "+v"(a), "+v"(b));
}

// ---------------- fused fp32 -> bf16 conversion, grid-strided ----------------
__global__ void cvt_all(const float* __restrict__ x,  const float* __restrict__ wq,
                        const float* __restrict__ wk, const float* __restrict__ wv,
                        const float* __restrict__ wo,
                        u16* __restrict__ xb, u16* __restrict__ wqkv,
                        u16* __restrict__ wob) {
  const int NX = (MM * DD) / 4;        // 2097152 chunks for x
  const int NW = (DD * DD) / 4;        // 1048576 chunks per weight
  const int total = NX + 4 * NW;       // 6291456
  for (int i = blockIdx.x * blockDim.x + threadIdx.x; i < total;
       i += gridDim.x * blockDim.x) {
    const float* s; u16* d; int off;
    if (i < NX) { s = x; d = xb; off = i; }
    else {
      int j = i - NX; int w = j >> 20; off = j & (NW - 1);
      s = (w == 0) ? wq : (w == 1) ? wk : (w == 2) ? wv : wo;
      d = (w < 3) ? (wqkv + (size_t)w * DD * DD) : wob;
    }
    f32x4 v = *(const f32x4*)(s + (size_t)off * 4);
    u16x4 o;
#pragma unroll
    for (int j = 0; j < 4; ++j) o[j] = f2bf(v[j]);
    *(u16x4*)(d + (size_t)off * 4) = o;
  }
}

// ---------------- GEMM: C[M,N] = A[M,K] * B[N,K]^T ----------------
// 128x128 tile, 4 waves (2x2, wave 64x64), BK=64 -> 128-byte LDS rows -> full
// (row&7) chunk-XOR swizzle (both sides: pre-swizzled global source + swizzled
// read) -> 0 bank conflicts (R10-proven). Double-buffered LDS (64 KB,
// 2 blocks/CU), raw s_barrier + counted vmcnt(8). Plain __launch_bounds__(256):
// R12's (256,5) capped VGPR below the live set -> accumulator spill to scratch
// (VGPR 48, FETCH 5x, 3.3x slower). Never cap VGPR below ~96 on this kernel.
// MODE 1: f32 out row-major (O-projection)
// MODE 4: QKV fused epilogue — region 0: rope*scale->Cq; 1: rope->Ck; 2: V^T->Cvt
template <int MODE>
__global__ __launch_bounds__(256) void gemm2(const u16* __restrict__ A,
                                             const u16* __restrict__ Bw,
                                             u16* __restrict__ Cq,
                                             u16* __restrict__ Ck,
                                             u16* __restrict__ Cvt,
                                             float* __restrict__ Cf,
                                             int M, int N, int K,
                                             const float* __restrict__ fc,
                                             const float* __restrict__ fs) {
  __shared__ __align__(16) u16 Al[2][128 * 64];
  __shared__ __align__(16) u16 Bl[2][128 * 64];
  const int tid  = threadIdx.x;
  const int wave = tid >> 6, lane = tid & 63;
  const int m0 = blockIdx.y * 128, n0 = blockIdx.x * 128;
  const int wr = (wave >> 1) * 64, wc = (wave & 1) * 64;
  const int lrow = lane & 15, kh = lane >> 4;
  const int sk = lrow & 7;             // read-side swizzle key

  f32x4 acc[4][4] = {};

  // stage K-tile T (A 128x64 + B 128x64) into buffer BUF: 8 loads/thread.
  // LDS dest linear; global source chunk pre-swizzled c ^= (row&7).
#define GSTAGE(T, BUF)                                                                  \
  {                                                                                     \
    int koff = (T) * 64;                                                                \
    _Pragma("unroll")                                                                   \
    for (int j_ = 0; j_ < 4; ++j_) {                                                    \
      int i_ = tid + j_ * 256;            /* 0..1023 */                                 \
      int r_ = i_ >> 3, c_ = i_ & 7;                                                    \
      int sc_ = (c_ ^ (r_ & 7)) * 8;                                                    \
      const u16* ga = A  + (size_t)(m0 + r_) * K + koff + sc_;                          \
      __builtin_amdgcn_global_load_lds((const __attribute__((address_space(1))) u32*)ga,\
                                       (__attribute__((address_space(3))) u32*)(&Al[BUF][0] + i_ * 8), \
                                       16, 0, 0);                                       \
      const u16* gb = Bw + (size_t)(n0 + r_) * K + koff + sc_;                          \
      __builtin_amdgcn_global_load_lds((const __attribute__((address_space(1))) u32*)gb,\
                                       (__attribute__((address_space(3))) u32*)(&Bl[BUF][0] + i_ * 8), \
                                       16, 0, 0);                                       \
    }                                                                                   \
  }

  const int NT = K / 64;               // 32
  GSTAGE(0, 0);
  for (int t = 0; t < NT; ++t) {
    const int bt = t & 1;
    if (t + 1 < NT) {
      GSTAGE(t + 1, bt ^ 1);
      asm volatile("s_waitcnt vmcnt(8)" ::: "memory");   // tile t's 8 loads resident
    } else {
      asm volatile("s_waitcnt vmcnt(0)" ::: "memory");
    }
    __builtin_amdgcn_s_barrier();       // tile t visible block-wide

    const u16* Ab = &Al[bt][0];
    const u16* Bb = &Bl[bt][0];
    short8 af[4][2], bf[4][2];
#pragma unroll
    for (int tt = 0; tt < 4; ++tt)
#pragma unroll
      for (int ks = 0; ks < 2; ++ks) {
        af[tt][ks] = *(const short8*)(Ab + (wr + tt * 16 + lrow) * 64 + ((ks * 4 + kh) ^ sk) * 8);
        bf[tt][ks] = *(const short8*)(Bb + (wc + tt * 16 + lrow) * 64 + ((ks * 4 + kh) ^ sk) * 8);
      }
#pragma unroll
    for (int mt = 0; mt < 4; ++mt)
#pragma unroll
      for (int nt = 0; nt < 4; ++nt)
#pragma unroll
        for (int ks = 0; ks < 2; ++ks)
          acc[mt][nt] = __builtin_amdgcn_mfma_f32_16x16x32_bf16(af[mt][ks], bf[nt][ks], acc[mt][nt], 0, 0, 0);

    __builtin_amdgcn_s_barrier();       // all reads of buf bt done before restage
  }
#undef GSTAGE

  const int dr = kh * 4;
  if constexpr (MODE == 1) {
#pragma unroll
    for (int mt = 0; mt < 4; ++mt)
#pragma unroll
      for (int nt = 0; nt < 4; ++nt)
#pragma unroll
        for (int i = 0; i < 4; ++i) {
          size_t r = (size_t)(m0 + wr + mt * 16 + dr + i);
          size_t c = (size_t)(n0 + wc + nt * 16 + lrow);
          Cf[r * N + c] = acc[mt][nt][i];
        }
  } else {
    const int region = n0 >> 11;        // 0:Q 1:K 2:V  (block-uniform)
    if (region < 2) {
      u16* Cd = region ? Ck : Cq;
      // Q pre-scaled by 1/sqrt(128)*log2e (attn works in exp2 domain)
      const float sfac = region ? 1.f : 0.08838834764831845f * 1.44269504088896340736f;
#pragma unroll
      for (int mt = 0; mt < 4; ++mt)
#pragma unroll
        for (int nt = 0; nt < 4; ++nt) {
          int c  = n0 + wc + nt * 16 + lrow;
          int cl = c & 2047;
          int dh = cl & 127, pi = dh >> 1;
          float sgn = (dh & 1) ? 1.f : -1.f;
#pragma unroll
          for (int i = 0; i < 4; ++i) {
            int r  = m0 + wr + mt * 16 + dr + i;
            int s_ = r & (SS - 1);
            float cc_ = fc[s_ * 64 + pi] * sfac;
            float ss_ = fs[s_ * 64 + pi] * (sgn * sfac);
            float v  = acc[mt][nt][i];
            float pv = __shfl_xor(v, 1, 64);
            Cd[(size_t)r * 2048 + cl] = f2bf(v * cc_ + pv * ss_);
          }
        }
    } else {
#pragma unroll
      for (int mt = 0; mt < 4; ++mt)
#pragma unroll
        for (int nt = 0; nt < 4; ++nt) {
          int cl = (n0 - 4096) + wc + nt * 16 + lrow;   // h*128+d
          int rr = m0 + wr + mt * 16 + dr;              // token, multiple of 4
          int b  = rr >> 11, s0 = rr & 2047;
          u16x4 pk;
#pragma unroll
          for (int i = 0; i < 4; ++i) pk[i] = f2bf(acc[mt][nt][i]);
          *(u16x4*)(Cvt + ((size_t)b * 2048 + cl) * 2048 + s0) = pk;
        }
    }
  }
}

// ---------------- Flash attention (causal), swapped 32x32, 2 blocks/CU ----------------
__global__ __launch_bounds__(256, 2) void attn_kernel(const u16* __restrict__ Q,
                                                      const u16* __restrict__ K,
                                                      const u16* __restrict__ Vt,
                                                      u16* __restrict__ O) {
  __shared__ __align__(16) u16 Kl[2][64 * 128];   // [buf][key][d], swizzled
  __shared__ __align__(16) u16 Vl[2][128 * 64];   // [buf][d][key], swizzled

  const int tid = threadIdx.x, wave = tid >> 6, lane = tid & 63;
  const int l31 = lane & 31, hi = lane >> 5;
  const int bh = blockIdx.x, b = bh >> 4, h = bh & 15;
  const int y = blockIdx.y;
  const int qt = (y < 8) ? y : (23 - y);
  const size_t base    = ((size_t)b * SS) * DD + (size_t)h * HDD;
  const size_t vt_base = (size_t)bh * HDD * SS;
  const int swz = (l31 & 7) << 4;                 // byte-domain LDS read swizzle

#define STAGE(KT, BUF)                                                              \
  {                                                                                 \
    int k0s = (KT) * 64;                                                            \
    _Pragma("unroll")                                                               \
    for (int i_ = 0; i_ < 4; ++i_) {                                                \
      int idx = tid + i_ * 256;                                                     \
      int kr = idx >> 4, c_ = idx & 15;                                             \
      const u16* gk = K + base + (size_t)(k0s + kr) * DD + ((c_ ^ (kr & 7)) * 8);   \
      __builtin_amdgcn_global_load_lds((const __attribute__((address_space(1))) u32*)gk, \
                                       (__attribute__((address_space(3))) u32*)(&Kl[BUF][0] + idx * 8), \
                                       16, 0, 0);                                   \
      int dv = idx >> 3, c2 = idx & 7;                                              \
      const u16* gv = Vt + vt_base + (size_t)dv * SS + k0s + ((c2 ^ (dv & 7)) * 8); \
      __builtin_amdgcn_global_load_lds((const __attribute__((address_space(1))) u32*)gv, \
                                       (__attribute__((address_space(3))) u32*)(&Vl[BUF][0] + idx * 8), \
                                       16, 0, 0);                                   \
    }                                                                               \
  }

  const int qw = qt * 128 + wave * 32;
  const int q_ = qw + l31;

  short8 qf[8];
#pragma unroll
  for (int kc = 0; kc < 8; ++kc)
    qf[kc] = *(const short8*)(Q + base + (size_t)(qw + l31) * DD + kc * 16 + hi * 8);

  f32x16 oacc[4] = {};
  float m_i = -1e30f, l_p = 0.f;

  int buf = 0;
  STAGE(0, 0);

  const int ntiles = 2 * qt + 2;
  for (int kt = 0; kt < ntiles; ++kt) {
    const int k0 = kt * 64;
    if (kt + 1 < ntiles) {
      STAGE(kt + 1, buf ^ 1);
      asm volatile("s_waitcnt vmcnt(8)" ::: "memory");
    } else {
      asm volatile("s_waitcnt vmcnt(0)" ::: "memory");
    }
    __builtin_amdgcn_s_barrier();

    if (k0 <= qw + 31) {
      const u16* Kb_ = &Kl[buf][0];
      const u16* Vb_ = &Vl[buf][0];

      f32x16 st[2] = {};
      __builtin_amdgcn_s_setprio(1);
#pragma unroll
      for (int kc = 0; kc < 8; ++kc) {
        int by0 = (l31 * 256)        + ((kc * 32 + hi * 16) ^ swz);
        int by1 = ((32 + l31) * 256) + ((kc * 32 + hi * 16) ^ swz);
        short8 a0 = *(const short8*)(Kb_ + (by0 >> 1));
        short8 a1 = *(const short8*)(Kb_ + (by1 >> 1));
        st[0] = __builtin_amdgcn_mfma_f32_32x32x16_bf16(a0, qf[kc], st[0], 0, 0, 0);
        st[1] = __builtin_amdgcn_mfma_f32_32x32x16_bf16(a1, qf[kc], st[1], 0, 0, 0);
      }
      __builtin_amdgcn_s_setprio(0);

      float mx = -1e30f;
      if (k0 + 63 > qw) {                           // diagonal tile only
#pragma unroll
        for (int kb = 0; kb < 2; ++kb)
#pragma unroll
          for (int r = 0; r < 16; ++r) {
            float s = st[kb][r];
            int key = k0 + kb * 32 + (r & 3) + ((r >> 2) << 3) + (hi << 2);
            if (key > q_) s = -1e30f;
            st[kb][r] = s;
            mx = fmaxf(mx, s);
          }
      } else {
#pragma unroll
        for (int kb = 0; kb < 2; ++kb)
#pragma unroll
          for (int r = 0; r < 16; ++r) mx = fmaxf(mx, st[kb][r]);
      }
      mx = fmaxf(mx, __shfl_xor(mx, 32, 64));

      if (__any(mx > m_i + 8.f)) {
        float mn  = fmaxf(m_i, mx);
        float esc = exp2f(m_i - mn);
        m_i = mn; l_p *= esc;
#pragma unroll
        for (int db = 0; db < 4; ++db)
#pragma unroll
          for (int r = 0; r < 16; ++r) oacc[db][r] *= esc;
      }
      float sum = 0.f;
#pragma unroll
      for (int kb = 0; kb < 2; ++kb)
#pragma unroll
        for (int r = 0; r < 16; ++r) {
          float e = exp2f(st[kb][r] - m_i);
          st[kb][r] = e;
          sum += e;
        }
      l_p += sum;

      __builtin_amdgcn_s_setprio(1);
#pragma unroll
      for (int kb = 0; kb < 2; ++kb) {
#pragma unroll
        for (int half = 0; half < 2; ++half) {
          const int rb = half * 8;
          u32 w0 = cvtpk(st[kb][rb + 0], st[kb][rb + 1]);
          u32 w1 = cvtpk(st[kb][rb + 2], st[kb][rb + 3]);
          u32 w2 = cvtpk(st[kb][rb + 4], st[kb][rb + 5]);
          u32 w3 = cvtpk(st[kb][rb + 6], st[kb][rb + 7]);
          permswap(w0, w2);
          permswap(w1, w3);
          short8 pf = __builtin_bit_cast(short8, (u32x4){w0, w1, w2, w3});
          const int ktv = kb * 2 + half;
#pragma unroll
          for (int db = 0; db < 4; ++db) {
            int d = db * 32 + l31;
            int by = d * 128 + ((ktv * 32 + hi * 16) ^ swz);
            short8 vf = *(const short8*)(Vb_ + (by >> 1));
            oacc[db] = __builtin_amdgcn_mfma_f32_32x32x16_bf16(vf, pf, oacc[db], 0, 0, 0);
          }
        }
      }
      __builtin_amdgcn_s_setprio(0);
    }
    __builtin_amdgcn_s_barrier();       // all reads of buf done before restage
    buf ^= 1;
  }

  float lt  = l_p + __shfl_xor(l_p, 32, 64);
  float inv = 1.f / lt;
#pragma unroll
  for (int db = 0; db < 4; ++db)
#pragma unroll
    for (int g = 0; g < 4; ++g) {
      int d0 = db * 32 + 8 * g + 4 * hi;
      u32x2 pk;
      pk[0] = cvtpk(oacc[db][4 * g + 0] * inv, oacc[db][4 * g + 1] * inv);
      pk[1] = cvtpk(oacc[db][4 * g + 2] * inv, oacc[db][4 * g + 3] * inv);
      *(u32x2*)(O + base + (size_t)q_ * DD + d0) = pk;
    }
#undef STAGE
}

// ---------------- launcher ----------------
extern "C" void kernel_launch(void* const* d_in, const int* in_sizes, int n_in,
                              void* d_out, int out_size, void* d_ws, size_t ws_size,
                              hipStream_t stream) {
  (void)in_sizes; (void)n_in; (void)out_size; (void)ws_size;
  const float* x  = (const float*)d_in[0];
  const float* wq = (const float*)d_in[1];
  const float* wk = (const float*)d_in[2];
  const float* wv = (const float*)d_in[3];
  const float* wo = (const float*)d_in[4];
  const float* fc = (const float*)d_in[5];
  const float* fs = (const float*)d_in[6];
  float* out = (float*)d_out;

  const size_t XBUF = (size_t)MM * DD * 2;     // 16.78 MB
  const size_t WBUF = (size_t)DD * DD * 2;     // 8.39 MB
  char* ws = (char*)d_ws;
  u16* xb   = (u16*)(ws);                      // reused as attn output Ob
  u16* Qb   = (u16*)(ws + XBUF);
  u16* Kb   = (u16*)(ws + 2 * XBUF);
  u16* Vtb  = (u16*)(ws + 3 * XBUF);
  u16* wqkv = (u16*)(ws + 4 * XBUF);           // [6144][2048]
  u16* wob  = (u16*)(ws + 4 * XBUF + 3 * WBUF);
  u16* Ob   = xb;

  cvt_all<<<2048, 256, 0, stream>>>(x, wq, wk, wv, wo, xb, wqkv, wob);

  // fused QKV projection: C[4096, 6144] with rope/transpose epilogue
  gemm2<4><<<dim3(48, 32), 256, 0, stream>>>(xb, wqkv, Qb, Kb, Vtb, nullptr,
                                             MM, 3 * DD, DD, fc, fs);

  attn_kernel<<<dim3(32, 16), 256, 0, stream>>>(Qb, Kb, Vtb, Ob);

  // O-projection: fp32 out
  gemm2<1><<<dim3(16, 32), 256, 0, stream>>>(Ob, wob, nullptr, nullptr, nullptr, out,
                                             MM, DD, DD, nullptr, nullptr);
}

// Round 14
// 245.843 us; speedup vs baseline: 2.7756x; 1.0091x over previous
//
#include <hip/hip_runtime.h>
#include <stdint.h>

// Problem: B=2, S=2048, D=2048, H=16, HD=128, M = B*S = 4096
#define BB  2
#define SS  2048
#define DD  2048
#define HH  16
#define HDD 128
#define MM  (BB * SS)

typedef __attribute__((ext_vector_type(8)))  short short8;
typedef __attribute__((ext_vector_type(4)))  float f32x4;
typedef __attribute__((ext_vector_type(16))) float f32x16;
typedef unsigned int   u32;
typedef unsigned short u16;
typedef __attribute__((ext_vector_type(4))) u16 u16x4;
typedef __attribute__((ext_vector_type(2))) u32 u32x2;
typedef __attribute__((ext_vector_type(4))) u32 u32x4;

static __device__ __forceinline__ u16 f2bf(float f) {
  u32 u = __builtin_bit_cast(u32, f);
  u32 r = u + 0x7fffu + ((u >> 16) & 1u);
  return (u16)(r >> 16);
}

static __device__ __forceinline__ u32 cvtpk(float a, float b) {
  u32 r;
  asm("v_cvt_pk_bf16_f32 %0, %1, %2" : "=v"(r) : "v"(a), "v"(b));
  return r;
}
static __device__ __forceinline__ void permswap(u32& a, u32& b) {
  asm volatile("v_permlane32_swap_b32 %0, %1" : "+v"(a), "+v"(b));
}

// ---------------- fused fp32 -> bf16 conversion, grid-strided ----------------
__global__ void cvt_all(const float* __restrict__ x,  const float* __restrict__ wq,
                        const float* __restrict__ wk, const float* __restrict__ wv,
                        const float* __restrict__ wo,
                        u16* __restrict__ xb, u16* __restrict__ wqkv,
                        u16* __restrict__ wob) {
  const int NX = (MM * DD) / 4;        // 2097152 chunks for x
  const int NW = (DD * DD) / 4;        // 1048576 chunks per weight
  const int total = NX + 4 * NW;       // 6291456
  for (int i = blockIdx.x * blockDim.x + threadIdx.x; i < total;
       i += gridDim.x * blockDim.x) {
    const float* s; u16* d; int off;
    if (i < NX) { s = x; d = xb; off = i; }
    else {
      int j = i - NX; int w = j >> 20; off = j & (NW - 1);
      s = (w == 0) ? wq : (w == 1) ? wk : (w == 2) ? wv : wo;
      d = (w < 3) ? (wqkv + (size_t)w * DD * DD) : wob;
    }
    f32x4 v = *(const f32x4*)(s + (size_t)off * 4);
    u16x4 o;
#pragma unroll
    for (int j = 0; j < 4; ++j) o[j] = f2bf(v[j]);
    *(u16x4*)(d + (size_t)off * 4) = o;
  }
}

// ---------------- GEMM: C[M,N] = A[M,K] * B[N,K]^T ----------------
// 128x128 tile, 4 waves, BK=64, SINGLE-buffered LDS (32 KB) + plain
// __launch_bounds__(256) -> VGPR 88 (4 waves/SIMD allowed), LDS allows 5
// blocks/CU -> net 4 blocks/CU = 16 waves/CU (2x the dbuf variant). m97/m114
// mechanism: cross-block wave TLP hides the per-tile staging drain; m99/m100
// showed explicit dbuf adds nothing once TLP exists. Chunk-XOR swizzle
// (source c^=(row&7), read (ks*4+kh)^(lrow&7)) -> 0 bank conflicts.
// CAUTION (R12 lesson): never add a min-waves launch-bound here — (256,5)
// capped VGPR to 48 < the 64-reg accumulator -> scratch spill, 3.3x slower.
// MODE 1: f32 out row-major (O-projection)
// MODE 4: QKV fused epilogue — region 0: rope*scale->Cq; 1: rope->Ck; 2: V^T->Cvt
template <int MODE>
__global__ __launch_bounds__(256) void gemm2(const u16* __restrict__ A,
                                             const u16* __restrict__ Bw,
                                             u16* __restrict__ Cq,
                                             u16* __restrict__ Ck,
                                             u16* __restrict__ Cvt,
                                             float* __restrict__ Cf,
                                             int M, int N, int K,
                                             const float* __restrict__ fc,
                                             const float* __restrict__ fs) {
  __shared__ __align__(16) u16 Al[128 * 64];
  __shared__ __align__(16) u16 Bl[128 * 64];
  const int tid  = threadIdx.x;
  const int wave = tid >> 6, lane = tid & 63;
  const int m0 = blockIdx.y * 128, n0 = blockIdx.x * 128;
  const int wr = (wave >> 1) * 64, wc = (wave & 1) * 64;
  const int lrow = lane & 15, kh = lane >> 4;
  const int sk = lrow & 7;             // read-side swizzle key

  f32x4 acc[4][4] = {};

  // stage K-tile T (A 128x64 + B 128x64): 8 loads/thread, linear LDS dest,
  // global source chunk pre-swizzled c ^= (row&7).
#define GSTAGE(T)                                                                       \
  {                                                                                     \
    int koff = (T) * 64;                                                                \
    _Pragma("unroll")                                                                   \
    for (int j_ = 0; j_ < 4; ++j_) {                                                    \
      int i_ = tid + j_ * 256;            /* 0..1023 */                                 \
      int r_ = i_ >> 3, c_ = i_ & 7;                                                    \
      int sc_ = (c_ ^ (r_ & 7)) * 8;                                                    \
      const u16* ga = A  + (size_t)(m0 + r_) * K + koff + sc_;                          \
      __builtin_amdgcn_global_load_lds((const __attribute__((address_space(1))) u32*)ga,\
                                       (__attribute__((address_space(3))) u32*)(Al + i_ * 8), \
                                       16, 0, 0);                                       \
      const u16* gb = Bw + (size_t)(n0 + r_) * K + koff + sc_;                          \
      __builtin_amdgcn_global_load_lds((const __attribute__((address_space(1))) u32*)gb,\
                                       (__attribute__((address_space(3))) u32*)(Bl + i_ * 8), \
                                       16, 0, 0);                                       \
    }                                                                                   \
  }

  const int NT = K / 64;               // 32
  for (int t = 0; t < NT; ++t) {
    if (t) __syncthreads();            // all reads of tile t-1 done before overwrite
    GSTAGE(t);
    __syncthreads();                   // drains vmcnt -> tile t visible block-wide

    short8 af[4][2], bf[4][2];
#pragma unroll
    for (int tt = 0; tt < 4; ++tt)
#pragma unroll
      for (int ks = 0; ks < 2; ++ks) {
        af[tt][ks] = *(const short8*)(Al + (wr + tt * 16 + lrow) * 64 + ((ks * 4 + kh) ^ sk) * 8);
        bf[tt][ks] = *(const short8*)(Bl + (wc + tt * 16 + lrow) * 64 + ((ks * 4 + kh) ^ sk) * 8);
      }
#pragma unroll
    for (int mt = 0; mt < 4; ++mt)
#pragma unroll
      for (int nt = 0; nt < 4; ++nt)
#pragma unroll
        for (int ks = 0; ks < 2; ++ks)
          acc[mt][nt] = __builtin_amdgcn_mfma_f32_16x16x32_bf16(af[mt][ks], bf[nt][ks], acc[mt][nt], 0, 0, 0);
  }
#undef GSTAGE

  const int dr = kh * 4;
  if constexpr (MODE == 1) {
#pragma unroll
    for (int mt = 0; mt < 4; ++mt)
#pragma unroll
      for (int nt = 0; nt < 4; ++nt)
#pragma unroll
        for (int i = 0; i < 4; ++i) {
          size_t r = (size_t)(m0 + wr + mt * 16 + dr + i);
          size_t c = (size_t)(n0 + wc + nt * 16 + lrow);
          Cf[r * N + c] = acc[mt][nt][i];
        }
  } else {
    const int region = n0 >> 11;        // 0:Q 1:K 2:V  (block-uniform)
    if (region < 2) {
      u16* Cd = region ? Ck : Cq;
      // Q pre-scaled by 1/sqrt(128)*log2e (attn works in exp2 domain)
      const float sfac = region ? 1.f : 0.08838834764831845f * 1.44269504088896340736f;
#pragma unroll
      for (int mt = 0; mt < 4; ++mt)
#pragma unroll
        for (int nt = 0; nt < 4; ++nt) {
          int c  = n0 + wc + nt * 16 + lrow;
          int cl = c & 2047;
          int dh = cl & 127, pi = dh >> 1;
          float sgn = (dh & 1) ? 1.f : -1.f;
#pragma unroll
          for (int i = 0; i < 4; ++i) {
            int r  = m0 + wr + mt * 16 + dr + i;
            int s_ = r & (SS - 1);
            float cc_ = fc[s_ * 64 + pi] * sfac;
            float ss_ = fs[s_ * 64 + pi] * (sgn * sfac);
            float v  = acc[mt][nt][i];
            float pv = __shfl_xor(v, 1, 64);
            Cd[(size_t)r * 2048 + cl] = f2bf(v * cc_ + pv * ss_);
          }
        }
    } else {
#pragma unroll
      for (int mt = 0; mt < 4; ++mt)
#pragma unroll
        for (int nt = 0; nt < 4; ++nt) {
          int cl = (n0 - 4096) + wc + nt * 16 + lrow;   // h*128+d
          int rr = m0 + wr + mt * 16 + dr;              // token, multiple of 4
          int b  = rr >> 11, s0 = rr & 2047;
          u16x4 pk;
#pragma unroll
          for (int i = 0; i < 4; ++i) pk[i] = f2bf(acc[mt][nt][i]);
          *(u16x4*)(Cvt + ((size_t)b * 2048 + cl) * 2048 + s0) = pk;
        }
    }
  }
}

// ---------------- Flash attention (causal), swapped 32x32, 2 blocks/CU ----------------
// (unchanged from R10/R13)
__global__ __launch_bounds__(256, 2) void attn_kernel(const u16* __restrict__ Q,
                                                      const u16* __restrict__ K,
                                                      const u16* __restrict__ Vt,
                                                      u16* __restrict__ O) {
  __shared__ __align__(16) u16 Kl[2][64 * 128];   // [buf][key][d], swizzled
  __shared__ __align__(16) u16 Vl[2][128 * 64];   // [buf][d][key], swizzled

  const int tid = threadIdx.x, wave = tid >> 6, lane = tid & 63;
  const int l31 = lane & 31, hi = lane >> 5;
  const int bh = blockIdx.x, b = bh >> 4, h = bh & 15;
  const int y = blockIdx.y;
  const int qt = (y < 8) ? y : (23 - y);
  const size_t base    = ((size_t)b * SS) * DD + (size_t)h * HDD;
  const size_t vt_base = (size_t)bh * HDD * SS;
  const int swz = (l31 & 7) << 4;                 // byte-domain LDS read swizzle

#define STAGE(KT, BUF)                                                              \
  {                                                                                 \
    int k0s = (KT) * 64;                                                            \
    _Pragma("unroll")                                                               \
    for (int i_ = 0; i_ < 4; ++i_) {                                                \
      int idx = tid + i_ * 256;                                                     \
      int kr = idx >> 4, c_ = idx & 15;                                             \
      const u16* gk = K + base + (size_t)(k0s + kr) * DD + ((c_ ^ (kr & 7)) * 8);   \
      __builtin_amdgcn_global_load_lds((const __attribute__((address_space(1))) u32*)gk, \
                                       (__attribute__((address_space(3))) u32*)(&Kl[BUF][0] + idx * 8), \
                                       16, 0, 0);                                   \
      int dv = idx >> 3, c2 = idx & 7;                                              \
      const u16* gv = Vt + vt_base + (size_t)dv * SS + k0s + ((c2 ^ (dv & 7)) * 8); \
      __builtin_amdgcn_global_load_lds((const __attribute__((address_space(1))) u32*)gv, \
                                       (__attribute__((address_space(3))) u32*)(&Vl[BUF][0] + idx * 8), \
                                       16, 0, 0);                                   \
    }                                                                               \
  }

  const int qw = qt * 128 + wave * 32;
  const int q_ = qw + l31;

  short8 qf[8];
#pragma unroll
  for (int kc = 0; kc < 8; ++kc)
    qf[kc] = *(const short8*)(Q + base + (size_t)(qw + l31) * DD + kc * 16 + hi * 8);

  f32x16 oacc[4] = {};
  float m_i = -1e30f, l_p = 0.f;

  int buf = 0;
  STAGE(0, 0);

  const int ntiles = 2 * qt + 2;
  for (int kt = 0; kt < ntiles; ++kt) {
    const int k0 = kt * 64;
    if (kt + 1 < ntiles) {
      STAGE(kt + 1, buf ^ 1);
      asm volatile("s_waitcnt vmcnt(8)" ::: "memory");
    } else {
      asm volatile("s_waitcnt vmcnt(0)" ::: "memory");
    }
    __builtin_amdgcn_s_barrier();

    if (k0 <= qw + 31) {
      const u16* Kb_ = &Kl[buf][0];
      const u16* Vb_ = &Vl[buf][0];

      f32x16 st[2] = {};
      __builtin_amdgcn_s_setprio(1);
#pragma unroll
      for (int kc = 0; kc < 8; ++kc) {
        int by0 = (l31 * 256)        + ((kc * 32 + hi * 16) ^ swz);
        int by1 = ((32 + l31) * 256) + ((kc * 32 + hi * 16) ^ swz);
        short8 a0 = *(const short8*)(Kb_ + (by0 >> 1));
        short8 a1 = *(const short8*)(Kb_ + (by1 >> 1));
        st[0] = __builtin_amdgcn_mfma_f32_32x32x16_bf16(a0, qf[kc], st[0], 0, 0, 0);
        st[1] = __builtin_amdgcn_mfma_f32_32x32x16_bf16(a1, qf[kc], st[1], 0, 0, 0);
      }
      __builtin_amdgcn_s_setprio(0);

      float mx = -1e30f;
      if (k0 + 63 > qw) {                           // diagonal tile only
#pragma unroll
        for (int kb = 0; kb < 2; ++kb)
#pragma unroll
          for (int r = 0; r < 16; ++r) {
            float s = st[kb][r];
            int key = k0 + kb * 32 + (r & 3) + ((r >> 2) << 3) + (hi << 2);
            if (key > q_) s = -1e30f;
            st[kb][r] = s;
            mx = fmaxf(mx, s);
          }
      } else {
#pragma unroll
        for (int kb = 0; kb < 2; ++kb)
#pragma unroll
          for (int r = 0; r < 16; ++r) mx = fmaxf(mx, st[kb][r]);
      }
      mx = fmaxf(mx, __shfl_xor(mx, 32, 64));

      if (__any(mx > m_i + 8.f)) {
        float mn  = fmaxf(m_i, mx);
        float esc = exp2f(m_i - mn);
        m_i = mn; l_p *= esc;
#pragma unroll
        for (int db = 0; db < 4; ++db)
#pragma unroll
          for (int r = 0; r < 16; ++r) oacc[db][r] *= esc;
      }
      float sum = 0.f;
#pragma unroll
      for (int kb = 0; kb < 2; ++kb)
#pragma unroll
        for (int r = 0; r < 16; ++r) {
          float e = exp2f(st[kb][r] - m_i);
          st[kb][r] = e;
          sum += e;
        }
      l_p += sum;

      __builtin_amdgcn_s_setprio(1);
#pragma unroll
      for (int kb = 0; kb < 2; ++kb) {
#pragma unroll
        for (int half = 0; half < 2; ++half) {
          const int rb = half * 8;
          u32 w0 = cvtpk(st[kb][rb + 0], st[kb][rb + 1]);
          u32 w1 = cvtpk(st[kb][rb + 2], st[kb][rb + 3]);
          u32 w2 = cvtpk(st[kb][rb + 4], st[kb][rb + 5]);
          u32 w3 = cvtpk(st[kb][rb + 6], st[kb][rb + 7]);
          permswap(w0, w2);
          permswap(w1, w3);
          short8 pf = __builtin_bit_cast(short8, (u32x4){w0, w1, w2, w3});
          const int ktv = kb * 2 + half;
#pragma unroll
          for (int db = 0; db < 4; ++db) {
            int d = db * 32 + l31;
            int by = d * 128 + ((ktv * 32 + hi * 16) ^ swz);
            short8 vf = *(const short8*)(Vb_ + (by >> 1));
            oacc[db] = __builtin_amdgcn_mfma_f32_32x32x16_bf16(vf, pf, oacc[db], 0, 0, 0);
          }
        }
      }
      __builtin_amdgcn_s_setprio(0);
    }
    __builtin_amdgcn_s_barrier();       // all reads of buf done before restage
    buf ^= 1;
  }

  float lt  = l_p + __shfl_xor(l_p, 32, 64);
  float inv = 1.f / lt;
#pragma unroll
  for (int db = 0; db < 4; ++db)
#pragma unroll
    for (int g = 0; g < 4; ++g) {
      int d0 = db * 32 + 8 * g + 4 * hi;
      u32x2 pk;
      pk[0] = cvtpk(oacc[db][4 * g + 0] * inv, oacc[db][4 * g + 1] * inv);
      pk[1] = cvtpk(oacc[db][4 * g + 2] * inv, oacc[db][4 * g + 3] * inv);
      *(u32x2*)(O + base + (size_t)q_ * DD + d0) = pk;
    }
#undef STAGE
}

// ---------------- launcher ----------------
extern "C" void kernel_launch(void* const* d_in, const int* in_sizes, int n_in,
                              void* d_out, int out_size, void* d_ws, size_t ws_size,
                              hipStream_t stream) {
  (void)in_sizes; (void)n_in; (void)out_size; (void)ws_size;
  const float* x  = (const float*)d_in[0];
  const float* wq = (const float*)d_in[1];
  const float* wk = (const float*)d_in[2];
  const float* wv = (const float*)d_in[3];
  const float* wo = (const float*)d_in[4];
  const float* fc = (const float*)d_in[5];
  const float* fs = (const float*)d_in[6];
  float* out = (float*)d_out;

  const size_t XBUF = (size_t)MM * DD * 2;     // 16.78 MB
  const size_t WBUF = (size_t)DD * DD * 2;     // 8.39 MB
  char* ws = (char*)d_ws;
  u16* xb   = (u16*)(ws);                      // reused as attn output Ob
  u16* Qb   = (u16*)(ws + XBUF);
  u16* Kb   = (u16*)(ws + 2 * XBUF);
  u16* Vtb  = (u16*)(ws + 3 * XBUF);
  u16* wqkv = (u16*)(ws + 4 * XBUF);           // [6144][2048]
  u16* wob  = (u16*)(ws + 4 * XBUF + 3 * WBUF);
  u16* Ob   = xb;

  cvt_all<<<2048, 256, 0, stream>>>(x, wq, wk, wv, wo, xb, wqkv, wob);

  // fused QKV projection: C[4096, 6144] with rope/transpose epilogue
  gemm2<4><<<dim3(48, 32), 256, 0, stream>>>(xb, wqkv, Qb, Kb, Vtb, nullptr,
                                             MM, 3 * DD, DD, fc, fs);

  attn_kernel<<<dim3(32, 16), 256, 0, stream>>>(Qb, Kb, Vtb, Ob);

  // O-projection: fp32 out
  gemm2<1><<<dim3(16, 32), 256, 0, stream>>>(Ob, wob, nullptr, nullptr, nullptr, out,
                                             MM, DD, DD, nullptr, nullptr);
}